// Round 10
// baseline (26414.157 us; speedup 1.0000x reference)
//
#include <hip/hip_runtime.h>
#include <stdint.h>

// ---------------------------------------------------------------------------
// TSCluster: 3x TransformerEncoderLayer (post-norm, relu) + cluster softmax +
// sequential HMM recursion.  N*P=131072 tokens, D=512, H=8, DFF=2048, C=32.
// bf16 activations + bf16 MFMA GEMMs (f32 accum), f32 LN/softmax.
// GEMM: 256x256 tile, BK=64, 8 waves, SINGLE-buffered 64 KiB LDS -> 2 blocks
// per CU (m97-style 2-barrier loop).  Six 1-block/CU schedule variants all
// plateaued at 337-385us; cross-block overlap replaces source pipelining.
// ---------------------------------------------------------------------------

typedef __bf16 bf16;
typedef __bf16 bf16x2 __attribute__((ext_vector_type(2)));
typedef __bf16 bf16x4 __attribute__((ext_vector_type(4)));
typedef __bf16 bf16x8 __attribute__((ext_vector_type(8)));
typedef float  f32x4  __attribute__((ext_vector_type(4)));
typedef float  f32x2  __attribute__((ext_vector_type(2)));

#define EPSF 1e-10f
#define NROWS 131072L   // N*P

__device__ __forceinline__ float bflo(uint32_t u){ return __uint_as_float(u << 16); }
__device__ __forceinline__ float bfhi(uint32_t u){ return __uint_as_float(u & 0xffff0000u); }

__device__ __forceinline__ void gload_lds16(const bf16* g, bf16* l){
  __builtin_amdgcn_global_load_lds((const __attribute__((address_space(1))) uint32_t*)g,
                                   (__attribute__((address_space(3))) uint32_t*)l,
                                   16, 0, 0);
}

// ---------------------------------------------------------------------------
__global__ void k_f2bf(const float* __restrict__ in, bf16* __restrict__ out, long n){
  const long stride = (long)gridDim.x * blockDim.x * 4;
  for (long i = ((long)blockIdx.x * blockDim.x + threadIdx.x) * 4; i < n; i += stride){
    f32x4 v = *(const f32x4*)(in + i);
    bf16x4 o = { (bf16)v[0], (bf16)v[1], (bf16)v[2], (bf16)v[3] };
    *(bf16x4*)(out + i) = o;
  }
}

// ---------------------------------------------------------------------------
// 256x256x64 8-wave GEMM: C[m,n] = A[m,k] * W[n,k] + bias[n]  (both K-contig)
// Wave output: rows {wr*64+[0,64)} u {128+wr*64+[0,64)},
//              cols {wc*32+[0,32)} u {128+wc*32+[0,32)}  (wr 0-1, wc 0-3)
// Single 64KB buffer; per K-tile: stage -> vmcnt(0) -> barrier -> read+MFMA
// (compiler-scheduled lgkm) -> barrier.  2 blocks/CU hide each other's stalls.

#define MFMA_PH(SM, SN)                                                       \
  {                                                                           \
    __builtin_amdgcn_s_setprio(1);                                            \
    _Pragma("unroll")                                                         \
    for (int kk = 0; kk < 2; kk++) {                                          \
      _Pragma("unroll")                                                       \
      for (int i2 = 0; i2 < 4; i2++) {                                        \
        _Pragma("unroll")                                                     \
        for (int j2 = 0; j2 < 2; j2++) {                                      \
          acc[(SM)*4+i2][(SN)*2+j2] = __builtin_amdgcn_mfma_f32_16x16x32_bf16(\
              a[i2][kk], b[SN][j2][kk], acc[(SM)*4+i2][(SN)*2+j2], 0, 0, 0);  \
        }                                                                     \
      }                                                                       \
    }                                                                         \
    __builtin_amdgcn_s_setprio(0);                                            \
  }

#define RD_A(SM)                                                              \
  _Pragma("unroll")                                                           \
  for (int i2 = 0; i2 < 4; i2++) {                                            \
    a[i2][0] = *(const bf16x8*)&As[(SM)*8192 + aBase + i2*1024 + sl0];        \
    a[i2][1] = *(const bf16x8*)&As[(SM)*8192 + aBase + i2*1024 + sl1];        \
  }

#define RD_B(SN)                                                              \
  _Pragma("unroll")                                                           \
  for (int j2 = 0; j2 < 2; j2++) {                                            \
    b[SN][j2][0] = *(const bf16x8*)&Bs[(SN)*8192 + bBase + j2*1024 + sl0];    \
    b[SN][j2][1] = *(const bf16x8*)&Bs[(SN)*8192 + bBase + j2*1024 + sl1];    \
  }

// one ISSUE = 64 rows x 64 k staged by 512 threads (8 rows per wave)
#define ISSUE_A(RO, KK) \
  gload_lds16(gA + (long)(RO)*lda + (KK), As + (RO)*64 + wsl)
#define ISSUE_B(RO, KK) \
  gload_lds16(gB + (long)(RO)*K   + (KK), Bs + (RO)*64 + wsl)

#define WAITV(N)  asm volatile("s_waitcnt vmcnt(" #N ")" ::: "memory")
#define WAITL0    asm volatile("s_waitcnt lgkmcnt(0)" ::: "memory")
#define BARRIER   { __builtin_amdgcn_s_barrier(); asm volatile("" ::: "memory"); }

template<int RELU>
__global__ __launch_bounds__(512, 4)
void gemm256(const bf16* __restrict__ A, long lda,
             const bf16* __restrict__ W,
             const float* __restrict__ bias,
             bf16* __restrict__ Cb, long K, int nbx)
{
  const int tid  = threadIdx.x;
  const int wid  = tid >> 6;
  const int lane = tid & 63;
  const int wr = wid >> 2, wc = wid & 3;
  const long ldc = (long)nbx * 256;

  // XCD-chunked block swizzle (nwg % 8 == 0 for all our shapes)
  const unsigned nwg = gridDim.x;
  const unsigned q   = nwg >> 3;
  const unsigned swz = (blockIdx.x & 7) * q + (blockIdx.x >> 3);
  const unsigned bx  = swz % (unsigned)nbx;
  const unsigned by  = swz / (unsigned)nbx;
  const long bm = (long)by * 256;
  const long bn = (long)bx * 256;

  __shared__ __align__(16) bf16 smem[32768];   // 64 KiB -> 2 blocks/CU
  bf16* const As = smem;
  bf16* const Bs = smem + 16384;

  // staging: per issue, wave w covers rows RO + w*8 .. +8; granule XOR swizzle
  const int gswz = ((lane & 7) ^ ((lane >> 3) & 7)) * 8;   // inverse swizzle
  const int wsl  = wid * 512;
  const bf16* gA = A + (bm + wid * 8 + (lane >> 3)) * lda + gswz;
  const bf16* gB = W + (bn + wid * 8 + (lane >> 3)) * K   + gswz;

  // fragment-read constants
  const int fr = lane & 15, fg = lane >> 4;
  const int aBase = (wr * 64 + fr) * 64;
  const int bBase = (wc * 32 + fr) * 64;
  const int sl0 = ((0 + fg) ^ (fr & 7)) * 8;
  const int sl1 = ((4 + fg) ^ (fr & 7)) * 8;

  f32x4 acc[8][4];
#pragma unroll
  for (int i = 0; i < 8; i++)
#pragma unroll
    for (int j = 0; j < 4; j++) acc[i][j] = (f32x4){0.f, 0.f, 0.f, 0.f};

  bf16x8 a[4][2];
  bf16x8 b[2][2][2];

  const int nt = (int)(K >> 6);

  for (int t = 0; t < nt; t++){
    const long k0 = (long)t << 6;
    // ---- stage tile t (8 x 8KB); own writes drained, then block-wide ----
    ISSUE_A(0, k0);   ISSUE_A(64, k0);
    ISSUE_B(0, k0);   ISSUE_B(64, k0);
    ISSUE_A(128, k0); ISSUE_A(192, k0);
    ISSUE_B(128, k0); ISSUE_B(192, k0);
    WAITV(0);
    BARRIER;
    // ---- read fragments + 64 MFMA; compiler interleaves lgkm waits ----
    RD_A(0); RD_B(0); RD_B(1);
    MFMA_PH(0, 0); MFMA_PH(0, 1);
    RD_A(1);
    MFMA_PH(1, 0); MFMA_PH(1, 1);
    BARRIER;   // every wave's ds_reads drained before next stage overwrites
  }

  // ---- epilogue: per-wave bf16 LDS roundtrip, [32][40] slice (80B rows) ----
  bf16* const cw = smem + wid * 1280;
  float bv[4];
#pragma unroll
  for (int sn = 0; sn < 2; sn++)
#pragma unroll
    for (int j2 = 0; j2 < 2; j2++)
      bv[sn * 2 + j2] = bias[bn + sn * 128 + wc * 32 + j2 * 16 + fr];

#pragma unroll
  for (int sm = 0; sm < 2; sm++){
#pragma unroll
    for (int sn = 0; sn < 2; sn++){
#pragma unroll
      for (int ch = 0; ch < 2; ch++){
#pragma unroll
        for (int i2 = 0; i2 < 2; i2++){
#pragma unroll
          for (int j2 = 0; j2 < 2; j2++){
#pragma unroll
            for (int r = 0; r < 4; r++){
              float v = acc[sm * 4 + ch * 2 + i2][sn * 2 + j2][r] + bv[sn * 2 + j2];
              if (RELU) v = fmaxf(v, 0.f);
              cw[(i2 * 16 + fg * 4 + r) * 40 + j2 * 16 + fr] = (bf16)v;
            }
          }
        }
        WAITL0;   // wave-local: ds_writes visible to own lanes' reads
        const long r0 = bm + sm * 128 + wr * 64 + ch * 32;
        const long c0 = bn + sn * 128 + wc * 32;
#pragma unroll
        for (int p = 0; p < 2; p++){
          const int row = p * 16 + (lane >> 2);
          const int colg = (lane & 3) * 8;
          bf16x8 o = *(const bf16x8*)&cw[row * 40 + colg];
          *(bf16x8*)&Cb[(r0 + row) * ldc + c0 + colg] = o;
        }
        WAITL0;   // reads done before next chunk overwrites the slice
      }
    }
  }
}

// ---------------------------------------------------------------------------
// Fused attention for one (n, h): Q,K,V are 64x64 bf16 slices of the qkv buffer
// [NROWS][1536].  O overwrites the Q slice.  scale = 1/sqrt(64) = 0.125.
__global__ __launch_bounds__(256)
void attention(bf16* __restrict__ qkv)
{
  const int blk = blockIdx.x;
  const long n = blk >> 3;
  const int h  = blk & 7;
  const int tid = threadIdx.x;
  const int wid = tid >> 6, lane = tid & 63;

  __shared__ __align__(16) bf16 Qs[64][72];
  __shared__ __align__(16) bf16 Ks[64][72];
  __shared__ __align__(16) bf16 Vt[64][72];

  bf16* base = qkv + n * 64 * 1536 + h * 64;

  for (int c = tid; c < 512; c += 256){
    const int row = c >> 3, col = (c & 7) * 8;
    const long go = (long)row * 1536 + col;
    *(bf16x8*)&Qs[row][col] = *(const bf16x8*)(base + go);
    *(bf16x8*)&Ks[row][col] = *(const bf16x8*)(base + 512 + go);
    bf16x8 v = *(const bf16x8*)(base + 1024 + go);
#pragma unroll
    for (int e = 0; e < 8; e++) Vt[col + e][row] = v[e];
  }
  __syncthreads();

  const int fr = lane & 15, fg = lane >> 4;
  f32x4 sacc[4];
#pragma unroll
  for (int j = 0; j < 4; j++) sacc[j] = (f32x4){0.f, 0.f, 0.f, 0.f};
#pragma unroll
  for (int ks = 0; ks < 2; ks++){
    bf16x8 aa = *(const bf16x8*)&Qs[wid * 16 + fr][ks * 32 + fg * 8];
#pragma unroll
    for (int j = 0; j < 4; j++){
      bf16x8 bb = *(const bf16x8*)&Ks[j * 16 + fr][ks * 32 + fg * 8];
      sacc[j] = __builtin_amdgcn_mfma_f32_16x16x32_bf16(aa, bb, sacc[j], 0, 0, 0);
    }
  }

  float pv[4][4];
#pragma unroll
  for (int r = 0; r < 4; r++){
    float m = -1e30f;
#pragma unroll
    for (int j = 0; j < 4; j++) m = fmaxf(m, sacc[j][r]);
#pragma unroll
    for (int msk = 1; msk < 16; msk <<= 1) m = fmaxf(m, __shfl_xor(m, msk));
    float s = 0.f;
#pragma unroll
    for (int j = 0; j < 4; j++){
      float p = __expf((sacc[j][r] - m) * 0.125f);
      pv[j][r] = p; s += p;
    }
#pragma unroll
    for (int msk = 1; msk < 16; msk <<= 1) s += __shfl_xor(s, msk);
    const float inv = 1.f / s;
#pragma unroll
    for (int j = 0; j < 4; j++) pv[j][r] *= inv;
  }

#pragma unroll
  for (int j = 0; j < 4; j++)
#pragma unroll
    for (int r = 0; r < 4; r++)
      Qs[wid * 16 + fg * 4 + r][j * 16 + fr] = (bf16)pv[j][r];
  __syncthreads();

  f32x4 oacc[4];
#pragma unroll
  for (int j = 0; j < 4; j++) oacc[j] = (f32x4){0.f, 0.f, 0.f, 0.f};
#pragma unroll
  for (int ks = 0; ks < 2; ks++){
    bf16x8 aa = *(const bf16x8*)&Qs[wid * 16 + fr][ks * 32 + fg * 8];
#pragma unroll
    for (int j = 0; j < 4; j++){
      bf16x8 bb = *(const bf16x8*)&Vt[j * 16 + fr][ks * 32 + fg * 8];
      oacc[j] = __builtin_amdgcn_mfma_f32_16x16x32_bf16(aa, bb, oacc[j], 0, 0, 0);
    }
  }
#pragma unroll
  for (int j = 0; j < 4; j++)
#pragma unroll
    for (int r = 0; r < 4; r++)
      base[(long)(wid * 16 + fg * 4 + r) * 1536 + j * 16 + fr] = (bf16)oacc[j][r];
}

// ---------------------------------------------------------------------------
// y = LayerNorm(x + o) * w + b ; one WAVE per row, 4 rows/block, no LDS.
// Optionally also writes the f32 result to EF (fused emb_ts output).
__global__ __launch_bounds__(256)
void resid_ln(const bf16* __restrict__ X, const bf16* __restrict__ O,
              const float* __restrict__ w, const float* __restrict__ b,
              bf16* __restrict__ Y, float* __restrict__ EF)
{
  const int wid = threadIdx.x >> 6, lane = threadIdx.x & 63;
  const long row = (long)blockIdx.x * 4 + wid;
  const uint4 xu = ((const uint4*)(X + row * 512))[lane];
  const uint4 ou = ((const uint4*)(O + row * 512))[lane];
  float s[8];
  s[0] = bflo(xu.x) + bflo(ou.x);  s[1] = bfhi(xu.x) + bfhi(ou.x);
  s[2] = bflo(xu.y) + bflo(ou.y);  s[3] = bfhi(xu.y) + bfhi(ou.y);
  s[4] = bflo(xu.z) + bflo(ou.z);  s[5] = bfhi(xu.z) + bfhi(ou.z);
  s[6] = bflo(xu.w) + bflo(ou.w);  s[7] = bfhi(xu.w) + bfhi(ou.w);
  float sum = 0.f, sq = 0.f;
#pragma unroll
  for (int e = 0; e < 8; e++){ sum += s[e]; sq += s[e] * s[e]; }
#pragma unroll
  for (int m = 1; m < 64; m <<= 1){ sum += __shfl_xor(sum, m); sq += __shfl_xor(sq, m); }
  const float mean = sum * (1.f / 512.f);
  const float var  = sq * (1.f / 512.f) - mean * mean;
  const float rs   = rsqrtf(var + 1e-5f);
  const f32x4 w0 = *(const f32x4*)(w + 8 * lane);
  const f32x4 w1 = *(const f32x4*)(w + 8 * lane + 4);
  const f32x4 b0 = *(const f32x4*)(b + 8 * lane);
  const f32x4 b1 = *(const f32x4*)(b + 8 * lane + 4);
  float o[8];
#pragma unroll
  for (int e = 0; e < 4; e++) o[e]     = (s[e]     - mean) * rs * w0[e] + b0[e];
#pragma unroll
  for (int e = 0; e < 4; e++) o[e + 4] = (s[e + 4] - mean) * rs * w1[e] + b1[e];
  bf16x8 ov = { (bf16)o[0], (bf16)o[1], (bf16)o[2], (bf16)o[3],
                (bf16)o[4], (bf16)o[5], (bf16)o[6], (bf16)o[7] };
  *(bf16x8*)(Y + row * 512 + 8 * lane) = ov;
  if (EF){
    f32x4 e0 = { o[0], o[1], o[2], o[3] };
    f32x4 e1 = { o[4], o[5], o[6], o[7] };
    *(f32x4*)(EF + row * 512 + 8 * lane) = e0;
    *(f32x4*)(EF + row * 512 + 8 * lane + 4) = e1;
  }
}

// ---------------------------------------------------------------------------
__global__ __launch_bounds__(256)
void k_mu(const float* __restrict__ mus, bf16* __restrict__ mubf, float* __restrict__ munorm)
{
  const int c = blockIdx.x, tid = threadIdx.x, lane = tid & 63, wid = tid >> 6;
  const f32x2 v = *(const f32x2*)(mus + c * 512 + 2 * tid);
  const float t0 = tanhf(v[0]), t1 = tanhf(v[1]);
  bf16x2 o2 = { (bf16)t0, (bf16)t1 };
  *(bf16x2*)(mubf + c * 512 + 2 * tid) = o2;
  float sq = t0 * t0 + t1 * t1;
#pragma unroll
  for (int m = 1; m < 64; m <<= 1) sq += __shfl_xor(sq, m);
  __shared__ float red[4];
  if (lane == 0) red[wid] = sq;
  __syncthreads();
  if (tid == 0) munorm[c] = red[0] + red[1] + red[2] + red[3];
}

// ---------------------------------------------------------------------------
__global__ __launch_bounds__(256)
void cluster_logza(const bf16* __restrict__ X, const bf16* __restrict__ MU,
                   const float* __restrict__ munorm, float* __restrict__ out)
{
  const int tid = threadIdx.x, lane = tid & 63, wid = tid >> 6;
  __shared__ __align__(16) bf16 mus[32][512];
  __shared__ float xs[512];
  __shared__ float red[4];
  __shared__ float dots[32];
  for (int c = tid; c < 2048; c += 256){
    const int r = c >> 6, col = (c & 63) * 8;
    *(bf16x8*)&mus[r][col] = *(const bf16x8*)(MU + r * 512 + col);
  }
  const int cc = tid >> 3, seg = tid & 7;
  const long row0 = (long)blockIdx.x * 16;
  __syncthreads();
  for (int rr = 0; rr < 16; rr++){
    const long row = row0 + rr;
    const uint32_t u = ((const uint32_t*)(X + row * 512))[tid];
    const float aa = bflo(u), bb = bfhi(u);
    xs[2 * tid] = aa; xs[2 * tid + 1] = bb;
    float sq = aa * aa + bb * bb;
#pragma unroll
    for (int m = 1; m < 64; m <<= 1) sq += __shfl_xor(sq, m);
    if (lane == 0) red[wid] = sq;
    __syncthreads();
    const float xn = red[0] + red[1] + red[2] + red[3];
    float p = 0.f;
#pragma unroll
    for (int jj = 0; jj < 8; jj++){
      const int col = jj * 64 + seg * 8;
      bf16x8 m8 = *(const bf16x8*)&mus[cc][col];
      const float* xv = &xs[col];
#pragma unroll
      for (int e = 0; e < 8; e++) p += xv[e] * (float)m8[e];
    }
#pragma unroll
    for (int m = 1; m < 8; m <<= 1) p += __shfl_xor(p, m);
    if (seg == 0) dots[cc] = p;
    __syncthreads();
    if (tid < 32){
      const float dist = xn + munorm[tid] - 2.f * dots[tid];
      const float lg = -dist * 0.1f;
      float mx = lg;
#pragma unroll
      for (int m = 1; m < 32; m <<= 1) mx = fmaxf(mx, __shfl_xor(mx, m, 32));
      const float z = __expf(lg - mx);
      float s = z;
#pragma unroll
      for (int m = 1; m < 32; m <<= 1) s += __shfl_xor(s, m, 32);
      out[row * 32 + tid] = logf(z / s + EPSF);
    }
    __syncthreads();
  }
}

// ---------------------------------------------------------------------------
__global__ __launch_bounds__(256)
void k_hmm(const float* __restrict__ lza, const float* __restrict__ pi,
           const float* __restrict__ A, float* __restrict__ cp, float* __restrict__ ent)
{
  __shared__ float As[32][33];
  const int tid = threadIdx.x;
  for (int i = tid; i < 1024; i += 256) As[i >> 5][i & 31] = A[i];
  __syncthreads();
  const int j = tid & 31;
  const long n = (long)blockIdx.x * 8 + (tid >> 5);
  const float* lz = lza + n * 2048;

  float c = logf(pi[j] + EPSF) + lz[j];
  {
    float mx = c;
#pragma unroll
    for (int m = 1; m < 32; m <<= 1) mx = fmaxf(mx, __shfl_xor(mx, m, 32));
    float z = __expf(c - mx), s = z;
#pragma unroll
    for (int m = 1; m < 32; m <<= 1) s += __shfl_xor(s, m, 32);
    c = z / s;
  }
  cp[n * 2048 + j] = c;
  float ea = -c * logf(c + EPSF);

  for (int p = 1; p < 64; p++){
    float y = 0.f;
#pragma unroll
    for (int i = 0; i < 32; i++) y += __shfl(c, i, 32) * As[i][j];
    float t = logf(y + EPSF) + lz[p * 32 + j];
    float mx = t;
#pragma unroll
    for (int m = 1; m < 32; m <<= 1) mx = fmaxf(mx, __shfl_xor(mx, m, 32));
    float z = __expf(t - mx), s = z;
#pragma unroll
    for (int m = 1; m < 32; m <<= 1) s += __shfl_xor(s, m, 32);
    c = z / s;
    cp[n * 2048 + p * 32 + j] = c;
    ea += -c * logf(c + EPSF);
  }
#pragma unroll
  for (int m = 1; m < 32; m <<= 1) ea += __shfl_xor(ea, m, 32);
  if (j == 0) atomicAdd(ent, ea * (1.f / 131072.f));
}

// ---------------------------------------------------------------------------
extern "C" void kernel_launch(void* const* d_in, const int* in_sizes, int n_in,
                              void* d_out, int out_size, void* d_ws, size_t ws_size,
                              hipStream_t stream)
{
  (void)in_sizes; (void)n_in; (void)out_size; (void)ws_size;
  const float* in_series = (const float*)d_in[0];
  const float* pi    = (const float*)d_in[1];
  const float* Amat  = (const float*)d_in[2];
  const float* qkv_w = (const float*)d_in[3];
  const float* qkv_b = (const float*)d_in[4];
  const float* out_w = (const float*)d_in[5];
  const float* out_b = (const float*)d_in[6];
  const float* ln1_w = (const float*)d_in[7];
  const float* ln1_b = (const float*)d_in[8];
  const float* ff1_w = (const float*)d_in[9];
  const float* ff1_b = (const float*)d_in[10];
  const float* ff2_w = (const float*)d_in[11];
  const float* ff2_b = (const float*)d_in[12];
  const float* ln2_w = (const float*)d_in[13];
  const float* ln2_b = (const float*)d_in[14];
  const float* mus   = (const float*)d_in[15];

  char* ws = (char*)d_ws;
  bf16* region0 = (bf16*)(ws);                         // 512MB: qkv / ffmid
  bf16* xb      = (bf16*)(ws + 536870912L);            // 128MB
  bf16* oproj   = (bf16*)(ws + 671088640L);            // 128MB
  bf16* w_qkv   = (bf16*)(ws + 805306368L);
  bf16* w_out   = (bf16*)(ws + 810024960L);
  bf16* w_ff1   = (bf16*)(ws + 811597824L);
  bf16* w_ff2   = (bf16*)(ws + 817889280L);
  bf16* mubf    = (bf16*)(ws + 824180736L);
  float* munorm = (float*)(ws + 824213504L);
  float* logza  = (float*)(ws);                        // aliases region0

  float* out_f = (float*)d_out;
  float* cp    = out_f;
  float* emb   = out_f + 4194304L;
  float* o_pi  = out_f + 71303168L;
  float* o_A   = out_f + 71303200L;
  float* o_ent = out_f + 71304224L;

  k_f2bf<<<8192, 256, 0, stream>>>(in_series, xb, 67108864L);
  k_f2bf<<<1024, 256, 0, stream>>>(qkv_w, w_qkv, 2359296L);
  k_f2bf<<<1024, 256, 0, stream>>>(out_w, w_out, 786432L);
  k_f2bf<<<1024, 256, 0, stream>>>(ff1_w, w_ff1, 3145728L);
  k_f2bf<<<1024, 256, 0, stream>>>(ff2_w, w_ff2, 3145728L);
  k_mu<<<32, 256, 0, stream>>>(mus, mubf, munorm);

  for (int l = 0; l < 3; l++){
    // qkv = x @ qkv_w^T + b   -> region0 [131072][1536]
    gemm256<0><<<3072, 512, 0, stream>>>(xb, 512, w_qkv + (long)l * 786432L,
                                         qkv_b + (long)l * 1536, region0, 512, 6);
    attention<<<16384, 256, 0, stream>>>(region0);
    // o @ out_w^T + b -> oproj
    gemm256<0><<<1024, 512, 0, stream>>>(region0, 1536, w_out + (long)l * 262144L,
                                         out_b + (long)l * 512, oproj, 512, 2);
    resid_ln<<<32768, 256, 0, stream>>>(xb, oproj, ln1_w + (long)l * 512,
                                        ln1_b + (long)l * 512, xb, nullptr);
    // ffmid = relu(x @ ff1_w^T + b) -> region0 [131072][2048]
    gemm256<1><<<4096, 512, 0, stream>>>(xb, 512, w_ff1 + (long)l * 1048576L,
                                         ff1_b + (long)l * 2048, region0, 512, 8);
    // ffout = ffmid @ ff2_w^T + b -> oproj
    gemm256<0><<<1024, 512, 0, stream>>>(region0, 2048, w_ff2 + (long)l * 1048576L,
                                         ff2_b + (long)l * 512, oproj, 2048, 2);
    // last layer: fuse f32 emb_ts output into the LN
    resid_ln<<<32768, 256, 0, stream>>>(xb, oproj, ln2_w + (long)l * 512,
                                        ln2_b + (long)l * 512, xb,
                                        (l == 2) ? emb : nullptr);
  }

  cluster_logza<<<8192, 256, 0, stream>>>(xb, mubf, munorm, logza);
  hipMemsetAsync(o_ent, 0, 4, stream);
  k_hmm<<<256, 256, 0, stream>>>(logza, pi, Amat, cp, o_ent);
  hipMemcpyAsync(o_pi, pi, 32 * sizeof(float), hipMemcpyDeviceToDevice, stream);
  hipMemcpyAsync(o_A, Amat, 1024 * sizeof(float), hipMemcpyDeviceToDevice, stream);
}

// Round 11
// 4060.744 us; speedup vs baseline: 6.5048x; 6.5048x over previous
//
#include <hip/hip_runtime.h>
#include <stdint.h>

// ---------------------------------------------------------------------------
// TSCluster: 3x TransformerEncoderLayer (post-norm, relu) + cluster softmax +
// sequential HMM recursion.  N*P=131072 tokens, D=512, H=8, DFF=2048, C=32.
// bf16 activations + bf16 MFMA GEMMs (f32 accum), f32 LN/softmax.
// GEMM: R7-verified 4-phase 256x256/BK64/8-wave schedule, now with TWO
// M-tiles per block (concatenated tile index, same wait ledger) to halve
// fill/drain, dedicated epilogue LDS region, and optional fused residual-add
// in the epilogue (out-proj / FF2) so the LN kernel reads one buffer.
// ---------------------------------------------------------------------------

typedef __bf16 bf16;
typedef __bf16 bf16x2 __attribute__((ext_vector_type(2)));
typedef __bf16 bf16x4 __attribute__((ext_vector_type(4)));
typedef __bf16 bf16x8 __attribute__((ext_vector_type(8)));
typedef float  f32x4  __attribute__((ext_vector_type(4)));
typedef float  f32x2  __attribute__((ext_vector_type(2)));

#define EPSF 1e-10f
#define NROWS 131072L   // N*P

__device__ __forceinline__ float bflo(uint32_t u){ return __uint_as_float(u << 16); }
__device__ __forceinline__ float bfhi(uint32_t u){ return __uint_as_float(u & 0xffff0000u); }

__device__ __forceinline__ void gload_lds16(const bf16* g, bf16* l){
  __builtin_amdgcn_global_load_lds((const __attribute__((address_space(1))) uint32_t*)g,
                                   (__attribute__((address_space(3))) uint32_t*)l,
                                   16, 0, 0);
}

// ---------------------------------------------------------------------------
__global__ void k_f2bf(const float* __restrict__ in, bf16* __restrict__ out, long n){
  const long stride = (long)gridDim.x * blockDim.x * 4;
  for (long i = ((long)blockIdx.x * blockDim.x + threadIdx.x) * 4; i < n; i += stride){
    f32x4 v = *(const f32x4*)(in + i);
    bf16x4 o = { (bf16)v[0], (bf16)v[1], (bf16)v[2], (bf16)v[3] };
    *(bf16x4*)(out + i) = o;
  }
}

// ---------------------------------------------------------------------------
// 256x256x64 8-wave GEMM, two M-tiles per block.
// Wave output per M-tile: rows {wr*64+[0,64)} u {128+wr*64+[0,64)},
//                         cols {wc*32+[0,32)} u {128+wc*32+[0,32)}
// Tile index t in [0, 2*nt): m-tile = t/nt, k-tile = t%nt.  The R7 ledger
// (P1-end WAITV(6), P4-end WAITV(8), tails 4/0) applies unchanged with T=2nt.
// Epilogue(m0) runs at t==nt-1 in a dedicated LDS region (no buffer clobber);
// its stores only make later vmcnt waits stricter (oldest-first retirement).

#define MFMA_PH(SM, SN)                                                       \
  {                                                                           \
    __builtin_amdgcn_s_setprio(1);                                            \
    _Pragma("unroll")                                                         \
    for (int kk = 0; kk < 2; kk++) {                                          \
      _Pragma("unroll")                                                       \
      for (int i2 = 0; i2 < 4; i2++) {                                        \
        _Pragma("unroll")                                                     \
        for (int j2 = 0; j2 < 2; j2++) {                                      \
          acc[(SM)*4+i2][(SN)*2+j2] = __builtin_amdgcn_mfma_f32_16x16x32_bf16(\
              a[i2][kk], b[SN][j2][kk], acc[(SM)*4+i2][(SN)*2+j2], 0, 0, 0);  \
        }                                                                     \
      }                                                                       \
    }                                                                         \
    __builtin_amdgcn_s_setprio(0);                                            \
  }

#define RD_A(SM)                                                              \
  _Pragma("unroll")                                                           \
  for (int i2 = 0; i2 < 4; i2++) {                                            \
    a[i2][0] = *(const bf16x8*)&Ac[(SM)*8192 + aBase + i2*1024 + sl0];        \
    a[i2][1] = *(const bf16x8*)&Ac[(SM)*8192 + aBase + i2*1024 + sl1];        \
  }

#define RD_B(SN)                                                              \
  _Pragma("unroll")                                                           \
  for (int j2 = 0; j2 < 2; j2++) {                                            \
    b[SN][j2][0] = *(const bf16x8*)&Bc[(SN)*8192 + bBase + j2*1024 + sl0];    \
    b[SN][j2][1] = *(const bf16x8*)&Bc[(SN)*8192 + bBase + j2*1024 + sl1];    \
  }

#define WAITV(N)  asm volatile("s_waitcnt vmcnt(" #N ")" ::: "memory")
#define WAITL0    asm volatile("s_waitcnt lgkmcnt(0)" ::: "memory")
#define BARRIER   { __builtin_amdgcn_s_barrier(); asm volatile("" ::: "memory"); }

#define ZERO_ACC                                                              \
  _Pragma("unroll") for (int zi = 0; zi < 8; zi++)                            \
  _Pragma("unroll") for (int zj = 0; zj < 4; zj++)                            \
    acc[zi][zj] = (f32x4){0.f, 0.f, 0.f, 0.f};

// epilogue for M-tile base BME: bias (+relu) (+residual) -> bf16, coalesced
// write via per-wave LDS slice in the dedicated region.
#define EPILOGUE(BME)                                                         \
{                                                                             \
  _Pragma("unroll")                                                           \
  for (int sm = 0; sm < 2; sm++){                                             \
    _Pragma("unroll")                                                         \
    for (int sn = 0; sn < 2; sn++){                                           \
      _Pragma("unroll")                                                       \
      for (int ch = 0; ch < 2; ch++){                                         \
        _Pragma("unroll")                                                     \
        for (int i2 = 0; i2 < 2; i2++){                                       \
          _Pragma("unroll")                                                   \
          for (int j2 = 0; j2 < 2; j2++){                                     \
            _Pragma("unroll")                                                 \
            for (int r = 0; r < 4; r++){                                      \
              float v = acc[sm*4 + ch*2 + i2][sn*2 + j2][r] + bv[sn*2 + j2];  \
              if (RELU) v = fmaxf(v, 0.f);                                    \
              cw[(i2*16 + fg*4 + r)*40 + j2*16 + fr] = (bf16)v;               \
            }                                                                 \
          }                                                                   \
        }                                                                     \
        WAITL0;                                                               \
        const long r0 = (BME) + sm*128 + wr*64 + ch*32;                       \
        const long c0 = bn + sn*128 + wc*32;                                  \
        _Pragma("unroll")                                                     \
        for (int p = 0; p < 2; p++){                                          \
          const int row  = p*16 + (lane >> 2);                                \
          const int colg = (lane & 3)*8;                                      \
          bf16x8 o = *(const bf16x8*)&cw[row*40 + colg];                      \
          if (HASRES){                                                        \
            bf16x8 rs8 = *(const bf16x8*)&RES[(r0+row)*ldc + c0 + colg];      \
            _Pragma("unroll")                                                 \
            for (int e = 0; e < 8; e++)                                       \
              o[e] = (bf16)((float)o[e] + (float)rs8[e]);                     \
          }                                                                   \
          *(bf16x8*)&Cb[(r0+row)*ldc + c0 + colg] = o;                        \
        }                                                                     \
        WAITL0;                                                               \
      }                                                                       \
    }                                                                         \
  }                                                                           \
}

template<int RELU, int HASRES>
__global__ __launch_bounds__(512, 2)
void gemm256(const bf16* __restrict__ A, long lda,
             const bf16* __restrict__ W,
             const float* __restrict__ bias,
             bf16* __restrict__ Cb,
             const bf16* __restrict__ RES,
             long K, int nbx)
{
  const int tid  = threadIdx.x;
  const int wid  = tid >> 6;
  const int lane = tid & 63;
  const int wr = wid >> 2, wc = wid & 3;
  const long ldc = (long)nbx * 256;

  // XCD-chunked block swizzle (nwg % 8 == 0 for all our shapes)
  const unsigned nwg = gridDim.x;
  const unsigned q   = nwg >> 3;
  const unsigned swz = (blockIdx.x & 7) * q + (blockIdx.x >> 3);
  const unsigned bx  = swz % (unsigned)nbx;
  const unsigned by  = swz / (unsigned)nbx;
  const long bm0 = (long)by * 512;        // M-tile pair: bm0, bm0+256
  const long bn  = (long)bx * 256;

  __shared__ __align__(16) bf16 smem[75776];   // 128 KiB buffers + 20 KiB epi
  bf16* const As0 = smem;
  bf16* const Bs0 = smem + 16384;
  bf16* const As1 = smem + 32768;
  bf16* const Bs1 = smem + 49152;
  bf16* const cw  = smem + 65536 + wid * 1280; // dedicated epilogue slice

  // staging: per issue, wave w covers rows RO + w*8 .. +8; granule XOR swizzle
  const int gswz = ((lane & 7) ^ ((lane >> 3) & 7)) * 8;   // inverse swizzle
  const int wsl  = wid * 512;
  const bf16* gA0 = A + (bm0 + wid * 8 + (lane >> 3)) * lda + gswz;
  const bf16* gA1 = gA0 + 256 * lda;
  const bf16* gB  = W + (bn + wid * 8 + (lane >> 3)) * K + gswz;

  // fragment-read constants
  const int fr = lane & 15, fg = lane >> 4;
  const int aBase = (wr * 64 + fr) * 64;
  const int bBase = (wc * 32 + fr) * 64;
  const int sl0 = ((0 + fg) ^ (fr & 7)) * 8;
  const int sl1 = ((4 + fg) ^ (fr & 7)) * 8;

  const int nt = (int)(K >> 6);
  const int T  = nt * 2;

  auto issueA = [&](bf16* dst, int ro, int tt){
    const bf16* g = (tt >= nt) ? gA1 : gA0;
    const long kk = (long)(tt >= nt ? tt - nt : tt) << 6;
    gload_lds16(g + (long)ro * lda + kk, dst + ro * 64 + wsl);
  };
  auto issueB = [&](bf16* dst, int ro, int tt){
    const long kk = (long)(tt >= nt ? tt - nt : tt) << 6;
    gload_lds16(gB + (long)ro * K + kk, dst + ro * 64 + wsl);
  };

  f32x4 acc[8][4];
  ZERO_ACC;

  bf16x8 a[4][2];
  bf16x8 b[2][2][2];

  float bv[4];
#pragma unroll
  for (int sn = 0; sn < 2; sn++)
#pragma unroll
    for (int j2 = 0; j2 < 2; j2++)
      bv[sn * 2 + j2] = bias[bn + sn * 128 + wc * 32 + j2 * 16 + fr];

  // ---- prologue: tile0 {A0,B0,A1,B1} + tile1 {A0,B0}; retire A0,B0(t0) ----
  issueA(As0, 0, 0);   issueA(As0, 64, 0);
  issueB(Bs0, 0, 0);   issueB(Bs0, 64, 0);
  issueA(As0, 128, 0); issueA(As0, 192, 0);
  issueB(Bs0, 128, 0); issueB(Bs0, 192, 0);
  issueA(As1, 0, 1);   issueA(As1, 64, 1);
  issueB(Bs1, 0, 1);   issueB(Bs1, 64, 1);
  WAITV(8);
  BARRIER;

  for (int t = 0; t < T; t++){
    bf16* const Ac = (t & 1) ? As1 : As0;
    bf16* const Bc = (t & 1) ? Bs1 : Bs0;
    bf16* const An = (t & 1) ? As0 : As1;
    bf16* const Bn = (t & 1) ? Bs0 : Bs1;
    const bool s1 = (t + 1 < T);
    const bool s2 = (t + 2 < T);

    // ---- phase 1: (m0,n0) ----
    RD_A(0); RD_B(0);
    if (s1){ issueA(An, 128, t + 1); issueA(An, 192, t + 1); }
    WAITL0;
    MFMA_PH(0, 0);
    if (s1){ WAITV(6); } else { WAITV(0); }   // A1(t),B1(t) landed for P2/P3
    BARRIER;

    // ---- phase 2: (m0,n1) ----
    RD_B(1);
    if (s1){ issueB(Bn, 128, t + 1); issueB(Bn, 192, t + 1); }
    WAITL0;
    MFMA_PH(0, 1);
    BARRIER;

    // ---- phase 3: (m1,n0) ----
    RD_A(1);
    if (s2){ issueA(Ac, 0, t + 2); issueA(Ac, 64, t + 2); }
    WAITL0;
    MFMA_PH(1, 0);
    BARRIER;

    // ---- phase 4: (m1,n1) ----
    if (s2){ issueB(Bc, 0, t + 2); issueB(Bc, 64, t + 2); }
    MFMA_PH(1, 1);
    if (s2)      { WAITV(8); }     // A0,B0(t+1) landed for next P1
    else if (s1) { WAITV(4); }
    BARRIER;

    // ---- seam: M-tile 0 done; epilogue overlaps m1's in-flight prefetch ----
    if (t == nt - 1){
      EPILOGUE(bm0);
      ZERO_ACC;
    }
  }

  EPILOGUE(bm0 + 256);
}

// ---------------------------------------------------------------------------
// Fused attention for one (n, h): Q,K,V are 64x64 bf16 slices of the qkv buffer
// [NROWS][1536].  O overwrites the Q slice.  scale = 1/sqrt(64) = 0.125.
__global__ __launch_bounds__(256)
void attention(bf16* __restrict__ qkv)
{
  const int blk = blockIdx.x;
  const long n = blk >> 3;
  const int h  = blk & 7;
  const int tid = threadIdx.x;
  const int wid = tid >> 6, lane = tid & 63;

  __shared__ __align__(16) bf16 Qs[64][72];
  __shared__ __align__(16) bf16 Ks[64][72];
  __shared__ __align__(16) bf16 Vt[64][72];

  bf16* base = qkv + n * 64 * 1536 + h * 64;

  for (int c = tid; c < 512; c += 256){
    const int row = c >> 3, col = (c & 7) * 8;
    const long go = (long)row * 1536 + col;
    *(bf16x8*)&Qs[row][col] = *(const bf16x8*)(base + go);
    *(bf16x8*)&Ks[row][col] = *(const bf16x8*)(base + 512 + go);
    bf16x8 v = *(const bf16x8*)(base + 1024 + go);
#pragma unroll
    for (int e = 0; e < 8; e++) Vt[col + e][row] = v[e];
  }
  __syncthreads();

  const int fr = lane & 15, fg = lane >> 4;
  f32x4 sacc[4];
#pragma unroll
  for (int j = 0; j < 4; j++) sacc[j] = (f32x4){0.f, 0.f, 0.f, 0.f};
#pragma unroll
  for (int ks = 0; ks < 2; ks++){
    bf16x8 aa = *(const bf16x8*)&Qs[wid * 16 + fr][ks * 32 + fg * 8];
#pragma unroll
    for (int j = 0; j < 4; j++){
      bf16x8 bb = *(const bf16x8*)&Ks[j * 16 + fr][ks * 32 + fg * 8];
      sacc[j] = __builtin_amdgcn_mfma_f32_16x16x32_bf16(aa, bb, sacc[j], 0, 0, 0);
    }
  }

  float pv[4][4];
#pragma unroll
  for (int r = 0; r < 4; r++){
    float m = -1e30f;
#pragma unroll
    for (int j = 0; j < 4; j++) m = fmaxf(m, sacc[j][r]);
#pragma unroll
    for (int msk = 1; msk < 16; msk <<= 1) m = fmaxf(m, __shfl_xor(m, msk));
    float s = 0.f;
#pragma unroll
    for (int j = 0; j < 4; j++){
      float p = __expf((sacc[j][r] - m) * 0.125f);
      pv[j][r] = p; s += p;
    }
#pragma unroll
    for (int msk = 1; msk < 16; msk <<= 1) s += __shfl_xor(s, msk);
    const float inv = 1.f / s;
#pragma unroll
    for (int j = 0; j < 4; j++) pv[j][r] *= inv;
  }

#pragma unroll
  for (int j = 0; j < 4; j++)
#pragma unroll
    for (int r = 0; r < 4; r++)
      Qs[wid * 16 + fg * 4 + r][j * 16 + fr] = (bf16)pv[j][r];
  __syncthreads();

  f32x4 oacc[4];
#pragma unroll
  for (int j = 0; j < 4; j++) oacc[j] = (f32x4){0.f, 0.f, 0.f, 0.f};
#pragma unroll
  for (int ks = 0; ks < 2; ks++){
    bf16x8 aa = *(const bf16x8*)&Qs[wid * 16 + fr][ks * 32 + fg * 8];
#pragma unroll
    for (int j = 0; j < 4; j++){
      bf16x8 bb = *(const bf16x8*)&Vt[j * 16 + fr][ks * 32 + fg * 8];
      oacc[j] = __builtin_amdgcn_mfma_f32_16x16x32_bf16(aa, bb, oacc[j], 0, 0, 0);
    }
  }
#pragma unroll
  for (int j = 0; j < 4; j++)
#pragma unroll
    for (int r = 0; r < 4; r++)
      base[(long)(wid * 16 + fg * 4 + r) * 1536 + j * 16 + fr] = (bf16)oacc[j][r];
}

// ---------------------------------------------------------------------------
// y = LayerNorm(s) * w + b ; s already holds (x + o) from the GEMM epilogue.
// One WAVE per row, 4 rows/block, no LDS.  Optional f32 emb output.
__global__ __launch_bounds__(256)
void ln_only(const bf16* __restrict__ S,
             const float* __restrict__ w, const float* __restrict__ b,
             bf16* __restrict__ Y, float* __restrict__ EF)
{
  const int wid = threadIdx.x >> 6, lane = threadIdx.x & 63;
  const long row = (long)blockIdx.x * 4 + wid;
  const uint4 su = ((const uint4*)(S + row * 512))[lane];
  float s[8];
  s[0] = bflo(su.x);  s[1] = bfhi(su.x);
  s[2] = bflo(su.y);  s[3] = bfhi(su.y);
  s[4] = bflo(su.z);  s[5] = bfhi(su.z);
  s[6] = bflo(su.w);  s[7] = bfhi(su.w);
  float sum = 0.f, sq = 0.f;
#pragma unroll
  for (int e = 0; e < 8; e++){ sum += s[e]; sq += s[e] * s[e]; }
#pragma unroll
  for (int m = 1; m < 64; m <<= 1){ sum += __shfl_xor(sum, m); sq += __shfl_xor(sq, m); }
  const float mean = sum * (1.f / 512.f);
  const float var  = sq * (1.f / 512.f) - mean * mean;
  const float rs   = rsqrtf(var + 1e-5f);
  const f32x4 w0 = *(const f32x4*)(w + 8 * lane);
  const f32x4 w1 = *(const f32x4*)(w + 8 * lane + 4);
  const f32x4 b0 = *(const f32x4*)(b + 8 * lane);
  const f32x4 b1 = *(const f32x4*)(b + 8 * lane + 4);
  float o[8];
#pragma unroll
  for (int e = 0; e < 4; e++) o[e]     = (s[e]     - mean) * rs * w0[e] + b0[e];
#pragma unroll
  for (int e = 0; e < 4; e++) o[e + 4] = (s[e + 4] - mean) * rs * w1[e] + b1[e];
  bf16x8 ov = { (bf16)o[0], (bf16)o[1], (bf16)o[2], (bf16)o[3],
                (bf16)o[4], (bf16)o[5], (bf16)o[6], (bf16)o[7] };
  *(bf16x8*)(Y + row * 512 + 8 * lane) = ov;
  if (EF){
    f32x4 e0 = { o[0], o[1], o[2], o[3] };
    f32x4 e1 = { o[4], o[5], o[6], o[7] };
    *(f32x4*)(EF + row * 512 + 8 * lane) = e0;
    *(f32x4*)(EF + row * 512 + 8 * lane + 4) = e1;
  }
}

// ---------------------------------------------------------------------------
__global__ __launch_bounds__(256)
void k_mu(const float* __restrict__ mus, bf16* __restrict__ mubf, float* __restrict__ munorm)
{
  const int c = blockIdx.x, tid = threadIdx.x, lane = tid & 63, wid = tid >> 6;
  const f32x2 v = *(const f32x2*)(mus + c * 512 + 2 * tid);
  const float t0 = tanhf(v[0]), t1 = tanhf(v[1]);
  bf16x2 o2 = { (bf16)t0, (bf16)t1 };
  *(bf16x2*)(mubf + c * 512 + 2 * tid) = o2;
  float sq = t0 * t0 + t1 * t1;
#pragma unroll
  for (int m = 1; m < 64; m <<= 1) sq += __shfl_xor(sq, m);
  __shared__ float red[4];
  if (lane == 0) red[wid] = sq;
  __syncthreads();
  if (tid == 0) munorm[c] = red[0] + red[1] + red[2] + red[3];
}

// ---------------------------------------------------------------------------
__global__ __launch_bounds__(256)
void cluster_logza(const bf16* __restrict__ X, const bf16* __restrict__ MU,
                   const float* __restrict__ munorm, float* __restrict__ out)
{
  const int tid = threadIdx.x, lane = tid & 63, wid = tid >> 6;
  __shared__ __align__(16) bf16 mus[32][512];
  __shared__ float xs[512];
  __shared__ float red[4];
  __shared__ float dots[32];
  for (int c = tid; c < 2048; c += 256){
    const int r = c >> 6, col = (c & 63) * 8;
    *(bf16x8*)&mus[r][col] = *(const bf16x8*)(MU + r * 512 + col);
  }
  const int cc = tid >> 3, seg = tid & 7;
  const long row0 = (long)blockIdx.x * 16;
  __syncthreads();
  for (int rr = 0; rr < 16; rr++){
    const long row = row0 + rr;
    const uint32_t u = ((const uint32_t*)(X + row * 512))[tid];
    const float aa = bflo(u), bb = bfhi(u);
    xs[2 * tid] = aa; xs[2 * tid + 1] = bb;
    float sq = aa * aa + bb * bb;
#pragma unroll
    for (int m = 1; m < 64; m <<= 1) sq += __shfl_xor(sq, m);
    if (lane == 0) red[wid] = sq;
    __syncthreads();
    const float xn = red[0] + red[1] + red[2] + red[3];
    float p = 0.f;
#pragma unroll
    for (int jj = 0; jj < 8; jj++){
      const int col = jj * 64 + seg * 8;
      bf16x8 m8 = *(const bf16x8*)&mus[cc][col];
      const float* xv = &xs[col];
#pragma unroll
      for (int e = 0; e < 8; e++) p += xv[e] * (float)m8[e];
    }
#pragma unroll
    for (int m = 1; m < 8; m <<= 1) p += __shfl_xor(p, m);
    if (seg == 0) dots[cc] = p;
    __syncthreads();
    if (tid < 32){
      const float dist = xn + munorm[tid] - 2.f * dots[tid];
      const float lg = -dist * 0.1f;
      float mx = lg;
#pragma unroll
      for (int m = 1; m < 32; m <<= 1) mx = fmaxf(mx, __shfl_xor(mx, m, 32));
      const float z = __expf(lg - mx);
      float s = z;
#pragma unroll
      for (int m = 1; m < 32; m <<= 1) s += __shfl_xor(s, m, 32);
      out[row * 32 + tid] = logf(z / s + EPSF);
    }
    __syncthreads();
  }
}

// ---------------------------------------------------------------------------
__global__ __launch_bounds__(256)
void k_hmm(const float* __restrict__ lza, const float* __restrict__ pi,
           const float* __restrict__ A, float* __restrict__ cp, float* __restrict__ ent)
{
  __shared__ float As[32][33];
  const int tid = threadIdx.x;
  for (int i = tid; i < 1024; i += 256) As[i >> 5][i & 31] = A[i];
  __syncthreads();
  const int j = tid & 31;
  const long n = (long)blockIdx.x * 8 + (tid >> 5);
  const float* lz = lza + n * 2048;

  float c = logf(pi[j] + EPSF) + lz[j];
  {
    float mx = c;
#pragma unroll
    for (int m = 1; m < 32; m <<= 1) mx = fmaxf(mx, __shfl_xor(mx, m, 32));
    float z = __expf(c - mx), s = z;
#pragma unroll
    for (int m = 1; m < 32; m <<= 1) s += __shfl_xor(s, m, 32);
    c = z / s;
  }
  cp[n * 2048 + j] = c;
  float ea = -c * logf(c + EPSF);

  for (int p = 1; p < 64; p++){
    float y = 0.f;
#pragma unroll
    for (int i = 0; i < 32; i++) y += __shfl(c, i, 32) * As[i][j];
    float t = logf(y + EPSF) + lz[p * 32 + j];
    float mx = t;
#pragma unroll
    for (int m = 1; m < 32; m <<= 1) mx = fmaxf(mx, __shfl_xor(mx, m, 32));
    float z = __expf(t - mx), s = z;
#pragma unroll
    for (int m = 1; m < 32; m <<= 1) s += __shfl_xor(s, m, 32);
    c = z / s;
    cp[n * 2048 + p * 32 + j] = c;
    ea += -c * logf(c + EPSF);
  }
#pragma unroll
  for (int m = 1; m < 32; m <<= 1) ea += __shfl_xor(ea, m, 32);
  if (j == 0) atomicAdd(ent, ea * (1.f / 131072.f));
}

// ---------------------------------------------------------------------------
extern "C" void kernel_launch(void* const* d_in, const int* in_sizes, int n_in,
                              void* d_out, int out_size, void* d_ws, size_t ws_size,
                              hipStream_t stream)
{
  (void)in_sizes; (void)n_in; (void)out_size; (void)ws_size;
  const float* in_series = (const float*)d_in[0];
  const float* pi    = (const float*)d_in[1];
  const float* Amat  = (const float*)d_in[2];
  const float* qkv_w = (const float*)d_in[3];
  const float* qkv_b = (const float*)d_in[4];
  const float* out_w = (const float*)d_in[5];
  const float* out_b = (const float*)d_in[6];
  const float* ln1_w = (const float*)d_in[7];
  const float* ln1_b = (const float*)d_in[8];
  const float* ff1_w = (const float*)d_in[9];
  const float* ff1_b = (const float*)d_in[10];
  const float* ff2_w = (const float*)d_in[11];
  const float* ff2_b = (const float*)d_in[12];
  const float* ln2_w = (const float*)d_in[13];
  const float* ln2_b = (const float*)d_in[14];
  const float* mus   = (const float*)d_in[15];

  char* ws = (char*)d_ws;
  bf16* region0 = (bf16*)(ws);                         // 512MB: qkv / ffmid
  bf16* xb      = (bf16*)(ws + 536870912L);            // 128MB
  bf16* oproj   = (bf16*)(ws + 671088640L);            // 128MB
  bf16* w_qkv   = (bf16*)(ws + 805306368L);
  bf16* w_out   = (bf16*)(ws + 810024960L);
  bf16* w_ff1   = (bf16*)(ws + 811597824L);
  bf16* w_ff2   = (bf16*)(ws + 817889280L);
  bf16* mubf    = (bf16*)(ws + 824180736L);
  float* munorm = (float*)(ws + 824213504L);
  float* logza  = (float*)(ws);                        // aliases region0

  float* out_f = (float*)d_out;
  float* cp    = out_f;
  float* emb   = out_f + 4194304L;
  float* o_pi  = out_f + 71303168L;
  float* o_A   = out_f + 71303200L;
  float* o_ent = out_f + 71304224L;

  k_f2bf<<<8192, 256, 0, stream>>>(in_series, xb, 67108864L);
  k_f2bf<<<1024, 256, 0, stream>>>(qkv_w, w_qkv, 2359296L);
  k_f2bf<<<1024, 256, 0, stream>>>(out_w, w_out, 786432L);
  k_f2bf<<<1024, 256, 0, stream>>>(ff1_w, w_ff1, 3145728L);
  k_f2bf<<<1024, 256, 0, stream>>>(ff2_w, w_ff2, 3145728L);
  k_mu<<<32, 256, 0, stream>>>(mus, mubf, munorm);

  for (int l = 0; l < 3; l++){
    // qkv = x @ qkv_w^T + b   -> region0 [131072][1536]
    gemm256<0,0><<<1536, 512, 0, stream>>>(xb, 512, w_qkv + (long)l * 786432L,
                                           qkv_b + (long)l * 1536, region0, nullptr,
                                           512, 6);
    attention<<<16384, 256, 0, stream>>>(region0);
    // oproj = x + (o @ out_w^T + b)   (residual fused in epilogue)
    gemm256<0,1><<<512, 512, 0, stream>>>(region0, 1536, w_out + (long)l * 262144L,
                                          out_b + (long)l * 512, oproj, xb,
                                          512, 2);
    ln_only<<<32768, 256, 0, stream>>>(oproj, ln1_w + (long)l * 512,
                                       ln1_b + (long)l * 512, xb, nullptr);
    // ffmid = relu(x @ ff1_w^T + b) -> region0 [131072][2048]
    gemm256<1,0><<<2048, 512, 0, stream>>>(xb, 512, w_ff1 + (long)l * 1048576L,
                                           ff1_b + (long)l * 2048, region0, nullptr,
                                           512, 8);
    // oproj = x + (ffmid @ ff2_w^T + b)
    gemm256<0,1><<<512, 512, 0, stream>>>(region0, 2048, w_ff2 + (long)l * 1048576L,
                                          ff2_b + (long)l * 512, oproj, xb,
                                          2048, 2);
    ln_only<<<32768, 256, 0, stream>>>(oproj, ln2_w + (long)l * 512,
                                       ln2_b + (long)l * 512, xb,
                                       (l == 2) ? emb : nullptr);
  }

  cluster_logza<<<8192, 256, 0, stream>>>(xb, mubf, munorm, logza);
  hipMemsetAsync(o_ent, 0, 4, stream);
  k_hmm<<<256, 256, 0, stream>>>(logza, pi, Amat, cp, o_ent);
  hipMemcpyAsync(o_pi, pi, 32 * sizeof(float), hipMemcpyDeviceToDevice, stream);
  hipMemcpyAsync(o_A, Amat, 1024 * sizeof(float), hipMemcpyDeviceToDevice, stream);
}

// Round 12
// 3916.106 us; speedup vs baseline: 6.7450x; 1.0369x over previous
//
#include <hip/hip_runtime.h>
#include <stdint.h>

// ---------------------------------------------------------------------------
// TSCluster: 3x TransformerEncoderLayer (post-norm, relu) + cluster softmax +
// sequential HMM recursion.  N*P=131072 tokens, D=512, H=8, DFF=2048, C=32.
// bf16 activations + bf16 MFMA GEMMs (f32 accum), f32 LN/softmax.
// GEMM: R7-verified 4-phase 256x256/BK64/8-wave schedule + two M-tiles per
// block (halved fill/drain; same wait ledger).  Residual fusion REVERTED
// (R11: cost ~190us + absmax headroom).  Attention: Vt transpose write-order
// swizzle kills the 8-way LDS bank conflict.
// ---------------------------------------------------------------------------

typedef __bf16 bf16;
typedef __bf16 bf16x2 __attribute__((ext_vector_type(2)));
typedef __bf16 bf16x4 __attribute__((ext_vector_type(4)));
typedef __bf16 bf16x8 __attribute__((ext_vector_type(8)));
typedef float  f32x4  __attribute__((ext_vector_type(4)));
typedef float  f32x2  __attribute__((ext_vector_type(2)));

#define EPSF 1e-10f
#define NROWS 131072L   // N*P

__device__ __forceinline__ float bflo(uint32_t u){ return __uint_as_float(u << 16); }
__device__ __forceinline__ float bfhi(uint32_t u){ return __uint_as_float(u & 0xffff0000u); }

__device__ __forceinline__ void gload_lds16(const bf16* g, bf16* l){
  __builtin_amdgcn_global_load_lds((const __attribute__((address_space(1))) uint32_t*)g,
                                   (__attribute__((address_space(3))) uint32_t*)l,
                                   16, 0, 0);
}

// ---------------------------------------------------------------------------
__global__ void k_f2bf(const float* __restrict__ in, bf16* __restrict__ out, long n){
  const long stride = (long)gridDim.x * blockDim.x * 4;
  for (long i = ((long)blockIdx.x * blockDim.x + threadIdx.x) * 4; i < n; i += stride){
    f32x4 v = *(const f32x4*)(in + i);
    bf16x4 o = { (bf16)v[0], (bf16)v[1], (bf16)v[2], (bf16)v[3] };
    *(bf16x4*)(out + i) = o;
  }
}

// ---------------------------------------------------------------------------
// 256x256x64 8-wave GEMM, two M-tiles per block (R7 ledger, T=2*nt).

#define MFMA_PH(SM, SN)                                                       \
  {                                                                           \
    __builtin_amdgcn_s_setprio(1);                                            \
    _Pragma("unroll")                                                         \
    for (int kk = 0; kk < 2; kk++) {                                          \
      _Pragma("unroll")                                                       \
      for (int i2 = 0; i2 < 4; i2++) {                                        \
        _Pragma("unroll")                                                     \
        for (int j2 = 0; j2 < 2; j2++) {                                      \
          acc[(SM)*4+i2][(SN)*2+j2] = __builtin_amdgcn_mfma_f32_16x16x32_bf16(\
              a[i2][kk], b[SN][j2][kk], acc[(SM)*4+i2][(SN)*2+j2], 0, 0, 0);  \
        }                                                                     \
      }                                                                       \
    }                                                                         \
    __builtin_amdgcn_s_setprio(0);                                            \
  }

#define RD_A(SM)                                                              \
  _Pragma("unroll")                                                           \
  for (int i2 = 0; i2 < 4; i2++) {                                            \
    a[i2][0] = *(const bf16x8*)&Ac[(SM)*8192 + aBase + i2*1024 + sl0];        \
    a[i2][1] = *(const bf16x8*)&Ac[(SM)*8192 + aBase + i2*1024 + sl1];        \
  }

#define RD_B(SN)                                                              \
  _Pragma("unroll")                                                           \
  for (int j2 = 0; j2 < 2; j2++) {                                            \
    b[SN][j2][0] = *(const bf16x8*)&Bc[(SN)*8192 + bBase + j2*1024 + sl0];    \
    b[SN][j2][1] = *(const bf16x8*)&Bc[(SN)*8192 + bBase + j2*1024 + sl1];    \
  }

#define WAITV(N)  asm volatile("s_waitcnt vmcnt(" #N ")" ::: "memory")
#define WAITL0    asm volatile("s_waitcnt lgkmcnt(0)" ::: "memory")
#define BARRIER   { __builtin_amdgcn_s_barrier(); asm volatile("" ::: "memory"); }

#define ZERO_ACC                                                              \
  _Pragma("unroll") for (int zi = 0; zi < 8; zi++)                            \
  _Pragma("unroll") for (int zj = 0; zj < 4; zj++)                            \
    acc[zi][zj] = (f32x4){0.f, 0.f, 0.f, 0.f};

// epilogue for M-tile base BME: bias (+relu) -> bf16, coalesced write via
// per-wave LDS slice in the dedicated region.
#define EPILOGUE(BME)                                                         \
{                                                                             \
  _Pragma("unroll")                                                           \
  for (int sm = 0; sm < 2; sm++){                                             \
    _Pragma("unroll")                                                         \
    for (int sn = 0; sn < 2; sn++){                                           \
      _Pragma("unroll")                                                       \
      for (int ch = 0; ch < 2; ch++){                                         \
        _Pragma("unroll")                                                     \
        for (int i2 = 0; i2 < 2; i2++){                                       \
          _Pragma("unroll")                                                   \
          for (int j2 = 0; j2 < 2; j2++){                                     \
            _Pragma("unroll")                                                 \
            for (int r = 0; r < 4; r++){                                      \
              float v = acc[sm*4 + ch*2 + i2][sn*2 + j2][r] + bv[sn*2 + j2];  \
              if (RELU) v = fmaxf(v, 0.f);                                    \
              cw[(i2*16 + fg*4 + r)*40 + j2*16 + fr] = (bf16)v;               \
            }                                                                 \
          }                                                                   \
        }                                                                     \
        WAITL0;                                                               \
        const long r0 = (BME) + sm*128 + wr*64 + ch*32;                       \
        const long c0 = bn + sn*128 + wc*32;                                  \
        _Pragma("unroll")                                                     \
        for (int p = 0; p < 2; p++){                                          \
          const int row  = p*16 + (lane >> 2);                                \
          const int colg = (lane & 3)*8;                                      \
          bf16x8 o = *(const bf16x8*)&cw[row*40 + colg];                      \
          *(bf16x8*)&Cb[(r0+row)*ldc + c0 + colg] = o;                        \
        }                                                                     \
        WAITL0;                                                               \
      }                                                                       \
    }                                                                         \
  }                                                                           \
}

template<int RELU>
__global__ __launch_bounds__(512, 2)
void gemm256(const bf16* __restrict__ A, long lda,
             const bf16* __restrict__ W,
             const float* __restrict__ bias,
             bf16* __restrict__ Cb,
             long K, int nbx)
{
  const int tid  = threadIdx.x;
  const int wid  = tid >> 6;
  const int lane = tid & 63;
  const int wr = wid >> 2, wc = wid & 3;
  const long ldc = (long)nbx * 256;

  // XCD-chunked block swizzle (nwg % 8 == 0 for all our shapes)
  const unsigned nwg = gridDim.x;
  const unsigned q   = nwg >> 3;
  const unsigned swz = (blockIdx.x & 7) * q + (blockIdx.x >> 3);
  const unsigned bx  = swz % (unsigned)nbx;
  const unsigned by  = swz / (unsigned)nbx;
  const long bm0 = (long)by * 512;        // M-tile pair: bm0, bm0+256
  const long bn  = (long)bx * 256;

  __shared__ __align__(16) bf16 smem[75776];   // 128 KiB buffers + 20 KiB epi
  bf16* const As0 = smem;
  bf16* const Bs0 = smem + 16384;
  bf16* const As1 = smem + 32768;
  bf16* const Bs1 = smem + 49152;
  bf16* const cw  = smem + 65536 + wid * 1280; // dedicated epilogue slice

  // staging: per issue, wave w covers rows RO + w*8 .. +8; granule XOR swizzle
  const int gswz = ((lane & 7) ^ ((lane >> 3) & 7)) * 8;   // inverse swizzle
  const int wsl  = wid * 512;
  const bf16* gA0 = A + (bm0 + wid * 8 + (lane >> 3)) * lda + gswz;
  const bf16* gA1 = gA0 + 256 * lda;
  const bf16* gB  = W + (bn + wid * 8 + (lane >> 3)) * K + gswz;

  // fragment-read constants
  const int fr = lane & 15, fg = lane >> 4;
  const int aBase = (wr * 64 + fr) * 64;
  const int bBase = (wc * 32 + fr) * 64;
  const int sl0 = ((0 + fg) ^ (fr & 7)) * 8;
  const int sl1 = ((4 + fg) ^ (fr & 7)) * 8;

  const int nt = (int)(K >> 6);
  const int T  = nt * 2;

  auto issueA = [&](bf16* dst, int ro, int tt){
    const bf16* g = (tt >= nt) ? gA1 : gA0;
    const long kk = (long)(tt >= nt ? tt - nt : tt) << 6;
    gload_lds16(g + (long)ro * lda + kk, dst + ro * 64 + wsl);
  };
  auto issueB = [&](bf16* dst, int ro, int tt){
    const long kk = (long)(tt >= nt ? tt - nt : tt) << 6;
    gload_lds16(gB + (long)ro * K + kk, dst + ro * 64 + wsl);
  };

  f32x4 acc[8][4];
  ZERO_ACC;

  bf16x8 a[4][2];
  bf16x8 b[2][2][2];

  float bv[4];
#pragma unroll
  for (int sn = 0; sn < 2; sn++)
#pragma unroll
    for (int j2 = 0; j2 < 2; j2++)
      bv[sn * 2 + j2] = bias[bn + sn * 128 + wc * 32 + j2 * 16 + fr];

  // ---- prologue: tile0 {A0,B0,A1,B1} + tile1 {A0,B0}; retire A0,B0(t0) ----
  issueA(As0, 0, 0);   issueA(As0, 64, 0);
  issueB(Bs0, 0, 0);   issueB(Bs0, 64, 0);
  issueA(As0, 128, 0); issueA(As0, 192, 0);
  issueB(Bs0, 128, 0); issueB(Bs0, 192, 0);
  issueA(As1, 0, 1);   issueA(As1, 64, 1);
  issueB(Bs1, 0, 1);   issueB(Bs1, 64, 1);
  WAITV(8);
  BARRIER;

  for (int t = 0; t < T; t++){
    bf16* const Ac = (t & 1) ? As1 : As0;
    bf16* const Bc = (t & 1) ? Bs1 : Bs0;
    bf16* const An = (t & 1) ? As0 : As1;
    bf16* const Bn = (t & 1) ? Bs0 : Bs1;
    const bool s1 = (t + 1 < T);
    const bool s2 = (t + 2 < T);

    // ---- phase 1: (m0,n0) ----
    RD_A(0); RD_B(0);
    if (s1){ issueA(An, 128, t + 1); issueA(An, 192, t + 1); }
    WAITL0;
    MFMA_PH(0, 0);
    if (s1){ WAITV(6); } else { WAITV(0); }   // A1(t),B1(t) landed for P2/P3
    BARRIER;

    // ---- phase 2: (m0,n1) ----
    RD_B(1);
    if (s1){ issueB(Bn, 128, t + 1); issueB(Bn, 192, t + 1); }
    WAITL0;
    MFMA_PH(0, 1);
    BARRIER;

    // ---- phase 3: (m1,n0) ----
    RD_A(1);
    if (s2){ issueA(Ac, 0, t + 2); issueA(Ac, 64, t + 2); }
    WAITL0;
    MFMA_PH(1, 0);
    BARRIER;

    // ---- phase 4: (m1,n1) ----
    if (s2){ issueB(Bc, 0, t + 2); issueB(Bc, 64, t + 2); }
    MFMA_PH(1, 1);
    if (s2)      { WAITV(8); }     // A0,B0(t+1) landed for next P1
    else if (s1) { WAITV(4); }
    BARRIER;

    // ---- seam: M-tile 0 done; epilogue overlaps m1's in-flight prefetch ----
    if (t == nt - 1){
      EPILOGUE(bm0);
      ZERO_ACC;
    }
  }

  EPILOGUE(bm0 + 256);
}

// ---------------------------------------------------------------------------
// Fused attention for one (n, h): Q,K,V are 64x64 bf16 slices of the qkv buffer
// [NROWS][1536].  O overwrites the Q slice.  scale = 1/sqrt(64) = 0.125.
// Vt transpose writes use a per-lane element-order permutation so the 8 lanes
// of a row-group hit 8 distinct 16B slots (was 8-way same-bank).
__global__ __launch_bounds__(256)
void attention(bf16* __restrict__ qkv)
{
  const int blk = blockIdx.x;
  const long n = blk >> 3;
  const int h  = blk & 7;
  const int tid = threadIdx.x;
  const int wid = tid >> 6, lane = tid & 63;

  __shared__ __align__(16) bf16 Qs[64][72];
  __shared__ __align__(16) bf16 Ks[64][72];
  __shared__ __align__(16) bf16 Vt[64][72];

  bf16* base = qkv + n * 64 * 1536 + h * 64;

  for (int c = tid; c < 512; c += 256){
    const int row = c >> 3, col = (c & 7) * 8, g = c & 7;
    const long go = (long)row * 1536 + col;
    *(bf16x8*)&Qs[row][col] = *(const bf16x8*)(base + go);
    *(bf16x8*)&Ks[row][col] = *(const bf16x8*)(base + 512 + go);
    bf16x8 v = *(const bf16x8*)(base + 1024 + go);
#pragma unroll
    for (int e = 0; e < 8; e++){
      const int vd = (e + g) & 7;          // write-order swizzle (layout same)
      Vt[col + vd][row] = v[vd];
    }
  }
  __syncthreads();

  const int fr = lane & 15, fg = lane >> 4;
  f32x4 sacc[4];
#pragma unroll
  for (int j = 0; j < 4; j++) sacc[j] = (f32x4){0.f, 0.f, 0.f, 0.f};
#pragma unroll
  for (int ks = 0; ks < 2; ks++){
    bf16x8 aa = *(const bf16x8*)&Qs[wid * 16 + fr][ks * 32 + fg * 8];
#pragma unroll
    for (int j = 0; j < 4; j++){
      bf16x8 bb = *(const bf16x8*)&Ks[j * 16 + fr][ks * 32 + fg * 8];
      sacc[j] = __builtin_amdgcn_mfma_f32_16x16x32_bf16(aa, bb, sacc[j], 0, 0, 0);
    }
  }

  float pv[4][4];
#pragma unroll
  for (int r = 0; r < 4; r++){
    float m = -1e30f;
#pragma unroll
    for (int j = 0; j < 4; j++) m = fmaxf(m, sacc[j][r]);
#pragma unroll
    for (int msk = 1; msk < 16; msk <<= 1) m = fmaxf(m, __shfl_xor(m, msk));
    float s = 0.f;
#pragma unroll
    for (int j = 0; j < 4; j++){
      float p = __expf((sacc[j][r] - m) * 0.125f);
      pv[j][r] = p; s += p;
    }
#pragma unroll
    for (int msk = 1; msk < 16; msk <<= 1) s += __shfl_xor(s, msk);
    const float inv = 1.f / s;
#pragma unroll
    for (int j = 0; j < 4; j++) pv[j][r] *= inv;
  }

#pragma unroll
  for (int j = 0; j < 4; j++)
#pragma unroll
    for (int r = 0; r < 4; r++)
      Qs[wid * 16 + fg * 4 + r][j * 16 + fr] = (bf16)pv[j][r];
  __syncthreads();

  f32x4 oacc[4];
#pragma unroll
  for (int j = 0; j < 4; j++) oacc[j] = (f32x4){0.f, 0.f, 0.f, 0.f};
#pragma unroll
  for (int ks = 0; ks < 2; ks++){
    bf16x8 aa = *(const bf16x8*)&Qs[wid * 16 + fr][ks * 32 + fg * 8];
#pragma unroll
    for (int j = 0; j < 4; j++){
      bf16x8 bb = *(const bf16x8*)&Vt[j * 16 + fr][ks * 32 + fg * 8];
      oacc[j] = __builtin_amdgcn_mfma_f32_16x16x32_bf16(aa, bb, oacc[j], 0, 0, 0);
    }
  }
#pragma unroll
  for (int j = 0; j < 4; j++)
#pragma unroll
    for (int r = 0; r < 4; r++)
      base[(long)(wid * 16 + fg * 4 + r) * 1536 + j * 16 + fr] = (bf16)oacc[j][r];
}

// ---------------------------------------------------------------------------
// y = LayerNorm(x + o) * w + b ; one WAVE per row, 4 rows/block, no LDS.
// Optionally also writes the f32 result to EF (fused emb_ts output).
__global__ __launch_bounds__(256)
void resid_ln(const bf16* __restrict__ X, const bf16* __restrict__ O,
              const float* __restrict__ w, const float* __restrict__ b,
              bf16* __restrict__ Y, float* __restrict__ EF)
{
  const int wid = threadIdx.x >> 6, lane = threadIdx.x & 63;
  const long row = (long)blockIdx.x * 4 + wid;
  const uint4 xu = ((const uint4*)(X + row * 512))[lane];
  const uint4 ou = ((const uint4*)(O + row * 512))[lane];
  float s[8];
  s[0] = bflo(xu.x) + bflo(ou.x);  s[1] = bfhi(xu.x) + bfhi(ou.x);
  s[2] = bflo(xu.y) + bflo(ou.y);  s[3] = bfhi(xu.y) + bfhi(ou.y);
  s[4] = bflo(xu.z) + bflo(ou.z);  s[5] = bfhi(xu.z) + bfhi(ou.z);
  s[6] = bflo(xu.w) + bflo(ou.w);  s[7] = bfhi(xu.w) + bfhi(ou.w);
  float sum = 0.f, sq = 0.f;
#pragma unroll
  for (int e = 0; e < 8; e++){ sum += s[e]; sq += s[e] * s[e]; }
#pragma unroll
  for (int m = 1; m < 64; m <<= 1){ sum += __shfl_xor(sum, m); sq += __shfl_xor(sq, m); }
  const float mean = sum * (1.f / 512.f);
  const float var  = sq * (1.f / 512.f) - mean * mean;
  const float rs   = rsqrtf(var + 1e-5f);
  const f32x4 w0 = *(const f32x4*)(w + 8 * lane);
  const f32x4 w1 = *(const f32x4*)(w + 8 * lane + 4);
  const f32x4 b0 = *(const f32x4*)(b + 8 * lane);
  const f32x4 b1 = *(const f32x4*)(b + 8 * lane + 4);
  float o[8];
#pragma unroll
  for (int e = 0; e < 4; e++) o[e]     = (s[e]     - mean) * rs * w0[e] + b0[e];
#pragma unroll
  for (int e = 0; e < 4; e++) o[e + 4] = (s[e + 4] - mean) * rs * w1[e] + b1[e];
  bf16x8 ov = { (bf16)o[0], (bf16)o[1], (bf16)o[2], (bf16)o[3],
                (bf16)o[4], (bf16)o[5], (bf16)o[6], (bf16)o[7] };
  *(bf16x8*)(Y + row * 512 + 8 * lane) = ov;
  if (EF){
    f32x4 e0 = { o[0], o[1], o[2], o[3] };
    f32x4 e1 = { o[4], o[5], o[6], o[7] };
    *(f32x4*)(EF + row * 512 + 8 * lane) = e0;
    *(f32x4*)(EF + row * 512 + 8 * lane + 4) = e1;
  }
}

// ---------------------------------------------------------------------------
__global__ __launch_bounds__(256)
void k_mu(const float* __restrict__ mus, bf16* __restrict__ mubf, float* __restrict__ munorm)
{
  const int c = blockIdx.x, tid = threadIdx.x, lane = tid & 63, wid = tid >> 6;
  const f32x2 v = *(const f32x2*)(mus + c * 512 + 2 * tid);
  const float t0 = tanhf(v[0]), t1 = tanhf(v[1]);
  bf16x2 o2 = { (bf16)t0, (bf16)t1 };
  *(bf16x2*)(mubf + c * 512 + 2 * tid) = o2;
  float sq = t0 * t0 + t1 * t1;
#pragma unroll
  for (int m = 1; m < 64; m <<= 1) sq += __shfl_xor(sq, m);
  __shared__ float red[4];
  if (lane == 0) red[wid] = sq;
  __syncthreads();
  if (tid == 0) munorm[c] = red[0] + red[1] + red[2] + red[3];
}

// ---------------------------------------------------------------------------
__global__ __launch_bounds__(256)
void cluster_logza(const bf16* __restrict__ X, const bf16* __restrict__ MU,
                   const float* __restrict__ munorm, float* __restrict__ out)
{
  const int tid = threadIdx.x, lane = tid & 63, wid = tid >> 6;
  __shared__ __align__(16) bf16 mus[32][512];
  __shared__ float xs[512];
  __shared__ float red[4];
  __shared__ float dots[32];
  for (int c = tid; c < 2048; c += 256){
    const int r = c >> 6, col = (c & 63) * 8;
    *(bf16x8*)&mus[r][col] = *(const bf16x8*)(MU + r * 512 + col);
  }
  const int cc = tid >> 3, seg = tid & 7;
  const long row0 = (long)blockIdx.x * 16;
  __syncthreads();
  for (int rr = 0; rr < 16; rr++){
    const long row = row0 + rr;
    const uint32_t u = ((const uint32_t*)(X + row * 512))[tid];
    const float aa = bflo(u), bb = bfhi(u);
    xs[2 * tid] = aa; xs[2 * tid + 1] = bb;
    float sq = aa * aa + bb * bb;
#pragma unroll
    for (int m = 1; m < 64; m <<= 1) sq += __shfl_xor(sq, m);
    if (lane == 0) red[wid] = sq;
    __syncthreads();
    const float xn = red[0] + red[1] + red[2] + red[3];
    float p = 0.f;
#pragma unroll
    for (int jj = 0; jj < 8; jj++){
      const int col = jj * 64 + seg * 8;
      bf16x8 m8 = *(const bf16x8*)&mus[cc][col];
      const float* xv = &xs[col];
#pragma unroll
      for (int e = 0; e < 8; e++) p += xv[e] * (float)m8[e];
    }
#pragma unroll
    for (int m = 1; m < 8; m <<= 1) p += __shfl_xor(p, m);
    if (seg == 0) dots[cc] = p;
    __syncthreads();
    if (tid < 32){
      const float dist = xn + munorm[tid] - 2.f * dots[tid];
      const float lg = -dist * 0.1f;
      float mx = lg;
#pragma unroll
      for (int m = 1; m < 32; m <<= 1) mx = fmaxf(mx, __shfl_xor(mx, m, 32));
      const float z = __expf(lg - mx);
      float s = z;
#pragma unroll
      for (int m = 1; m < 32; m <<= 1) s += __shfl_xor(s, m, 32);
      out[row * 32 + tid] = logf(z / s + EPSF);
    }
    __syncthreads();
  }
}

// ---------------------------------------------------------------------------
__global__ __launch_bounds__(256)
void k_hmm(const float* __restrict__ lza, const float* __restrict__ pi,
           const float* __restrict__ A, float* __restrict__ cp, float* __restrict__ ent)
{
  __shared__ float As[32][33];
  const int tid = threadIdx.x;
  for (int i = tid; i < 1024; i += 256) As[i >> 5][i & 31] = A[i];
  __syncthreads();
  const int j = tid & 31;
  const long n = (long)blockIdx.x * 8 + (tid >> 5);
  const float* lz = lza + n * 2048;

  float c = logf(pi[j] + EPSF) + lz[j];
  {
    float mx = c;
#pragma unroll
    for (int m = 1; m < 32; m <<= 1) mx = fmaxf(mx, __shfl_xor(mx, m, 32));
    float z = __expf(c - mx), s = z;
#pragma unroll
    for (int m = 1; m < 32; m <<= 1) s += __shfl_xor(s, m, 32);
    c = z / s;
  }
  cp[n * 2048 + j] = c;
  float ea = -c * logf(c + EPSF);

  for (int p = 1; p < 64; p++){
    float y = 0.f;
#pragma unroll
    for (int i = 0; i < 32; i++) y += __shfl(c, i, 32) * As[i][j];
    float t = logf(y + EPSF) + lz[p * 32 + j];
    float mx = t;
#pragma unroll
    for (int m = 1; m < 32; m <<= 1) mx = fmaxf(mx, __shfl_xor(mx, m, 32));
    float z = __expf(t - mx), s = z;
#pragma unroll
    for (int m = 1; m < 32; m <<= 1) s += __shfl_xor(s, m, 32);
    c = z / s;
    cp[n * 2048 + p * 32 + j] = c;
    ea += -c * logf(c + EPSF);
  }
#pragma unroll
  for (int m = 1; m < 32; m <<= 1) ea += __shfl_xor(ea, m, 32);
  if (j == 0) atomicAdd(ent, ea * (1.f / 131072.f));
}

// ---------------------------------------------------------------------------
extern "C" void kernel_launch(void* const* d_in, const int* in_sizes, int n_in,
                              void* d_out, int out_size, void* d_ws, size_t ws_size,
                              hipStream_t stream)
{
  (void)in_sizes; (void)n_in; (void)out_size; (void)ws_size;
  const float* in_series = (const float*)d_in[0];
  const float* pi    = (const float*)d_in[1];
  const float* Amat  = (const float*)d_in[2];
  const float* qkv_w = (const float*)d_in[3];
  const float* qkv_b = (const float*)d_in[4];
  const float* out_w = (const float*)d_in[5];
  const float* out_b = (const float*)d_in[6];
  const float* ln1_w = (const float*)d_in[7];
  const float* ln1_b = (const float*)d_in[8];
  const float* ff1_w = (const float*)d_in[9];
  const float* ff1_b = (const float*)d_in[10];
  const float* ff2_w = (const float*)d_in[11];
  const float* ff2_b = (const float*)d_in[12];
  const float* ln2_w = (const float*)d_in[13];
  const float* ln2_b = (const float*)d_in[14];
  const float* mus   = (const float*)d_in[15];

  char* ws = (char*)d_ws;
  bf16* region0 = (bf16*)(ws);                         // 512MB: qkv / ffmid
  bf16* xb      = (bf16*)(ws + 536870912L);            // 128MB
  bf16* oproj   = (bf16*)(ws + 671088640L);            // 128MB
  bf16* w_qkv   = (bf16*)(ws + 805306368L);
  bf16* w_out   = (bf16*)(ws + 810024960L);
  bf16* w_ff1   = (bf16*)(ws + 811597824L);
  bf16* w_ff2   = (bf16*)(ws + 817889280L);
  bf16* mubf    = (bf16*)(ws + 824180736L);
  float* munorm = (float*)(ws + 824213504L);
  float* logza  = (float*)(ws);                        // aliases region0

  float* out_f = (float*)d_out;
  float* cp    = out_f;
  float* emb   = out_f + 4194304L;
  float* o_pi  = out_f + 71303168L;
  float* o_A   = out_f + 71303200L;
  float* o_ent = out_f + 71304224L;

  k_f2bf<<<8192, 256, 0, stream>>>(in_series, xb, 67108864L);
  k_f2bf<<<1024, 256, 0, stream>>>(qkv_w, w_qkv, 2359296L);
  k_f2bf<<<1024, 256, 0, stream>>>(out_w, w_out, 786432L);
  k_f2bf<<<1024, 256, 0, stream>>>(ff1_w, w_ff1, 3145728L);
  k_f2bf<<<1024, 256, 0, stream>>>(ff2_w, w_ff2, 3145728L);
  k_mu<<<32, 256, 0, stream>>>(mus, mubf, munorm);

  for (int l = 0; l < 3; l++){
    // qkv = x @ qkv_w^T + b   -> region0 [131072][1536]
    gemm256<0><<<1536, 512, 0, stream>>>(xb, 512, w_qkv + (long)l * 786432L,
                                         qkv_b + (long)l * 1536, region0, 512, 6);
    attention<<<16384, 256, 0, stream>>>(region0);
    // o @ out_w^T + b -> oproj
    gemm256<0><<<512, 512, 0, stream>>>(region0, 1536, w_out + (long)l * 262144L,
                                        out_b + (long)l * 512, oproj, 512, 2);
    resid_ln<<<32768, 256, 0, stream>>>(xb, oproj, ln1_w + (long)l * 512,
                                        ln1_b + (long)l * 512, xb, nullptr);
    // ffmid = relu(x @ ff1_w^T + b) -> region0 [131072][2048]
    gemm256<1><<<2048, 512, 0, stream>>>(xb, 512, w_ff1 + (long)l * 1048576L,
                                         ff1_b + (long)l * 2048, region0, 512, 8);
    // ffout = ffmid @ ff2_w^T + b -> oproj
    gemm256<0><<<512, 512, 0, stream>>>(region0, 2048, w_ff2 + (long)l * 1048576L,
                                        ff2_b + (long)l * 512, oproj, 2048, 2);
    // last layer: fuse f32 emb_ts output into the LN
    resid_ln<<<32768, 256, 0, stream>>>(xb, oproj, ln2_w + (long)l * 512,
                                        ln2_b + (long)l * 512, xb,
                                        (l == 2) ? emb : nullptr);
  }

  cluster_logza<<<8192, 256, 0, stream>>>(xb, mubf, munorm, logza);
  hipMemsetAsync(o_ent, 0, 4, stream);
  k_hmm<<<256, 256, 0, stream>>>(logza, pi, Amat, cp, o_ent);
  hipMemcpyAsync(o_pi, pi, 32 * sizeof(float), hipMemcpyDeviceToDevice, stream);
  hipMemcpyAsync(o_A, Amat, 1024 * sizeof(float), hipMemcpyDeviceToDevice, stream);
}